// Round 1
// baseline (1422.820 us; speedup 1.0000x reference)
//
#include <hip/hip_runtime.h>
#include <math.h>

#define BB   1024
#define NN   256
#define FF   64
#define FSS  128
#define OUTT 128
#define SS   4
#define HH   4
#define KK   4
#define HDD  16
#define EPSF 1e-5f
#define BIGF 1000000000.0f

// ---------------------------------------------------------------- K1: attention + assign + sf
__global__ __launch_bounds__(256) void k_attn_sf(
    const float* __restrict__ axle, const float* __restrict__ sq,
    const float* __restrict__ wq, const float* __restrict__ bq,
    const float* __restrict__ wk, const float* __restrict__ bk,
    const float* __restrict__ w_a2s, const float* __restrict__ b_a2s,
    float* __restrict__ assign_o, float* __restrict__ sf_o)
{
  const int b = blockIdx.x, tid = threadIdx.x;
  const int wv = tid >> 6, ln = tid & 63;
  __shared__ float x_s[NN*(FF+1)];      // padded rows: bank-conflict-free row reads
  __shared__ float sq_s[SS*FF];
  __shared__ float q_s[SS*FF];
  __shared__ float sc_s[HH*SS][NN];
  __shared__ float mz_s[HH*SS][2];
  __shared__ float as_s[NN][SS];
  __shared__ float t_s[SS][FF];
  __shared__ float As_s[SS];

  sq_s[tid] = sq[tid];                  // SS*FF == 256 == blockDim
  const float* afb = axle + (size_t)b*NN*FF;
  for (int i = tid; i < NN*FF; i += 256)
    x_s[(i>>6)*(FF+1) + (i&63)] = afb[i];
  __syncthreads();

  // q projection (4x64 = 256 outputs, one per thread)
  {
    int s = tid >> 6, f = tid & 63;
    float acc = bq[f];
    for (int c = 0; c < FF; ++c) acc += sq_s[s*FF+c] * wq[c*FF+f];
    q_s[s*FF+f] = acc;
  }
  __syncthreads();

  // k-projection + scores, thread = node
  {
    float acc[FF];
    #pragma unroll
    for (int f = 0; f < FF; ++f) acc[f] = bk[f];
    for (int c = 0; c < FF; ++c) {
      float xc = x_s[tid*(FF+1)+c];
      #pragma unroll
      for (int f = 0; f < FF; ++f) acc[f] += xc * wk[c*FF+f];   // wk uniform -> s_load
    }
    #pragma unroll
    for (int h = 0; h < HH; ++h) {
      #pragma unroll
      for (int s = 0; s < SS; ++s) {
        float sc = 0.f;
        #pragma unroll
        for (int d = 0; d < HDD; ++d) sc += q_s[s*FF + h*HDD + d] * acc[h*HDD + d];
        sc_s[h*SS+s][tid] = sc * 0.25f;   // / sqrt(16)
      }
    }
  }
  __syncthreads();

  // softmax over N for each of the 16 (h,s) rows: wave wv handles rows wv*4..wv*4+3
  for (int r = 0; r < 4; ++r) {
    int row = wv*4 + r;
    float m = -3.4e38f;
    for (int j = ln; j < NN; j += 64) m = fmaxf(m, sc_s[row][j]);
    #pragma unroll
    for (int o = 32; o; o >>= 1) m = fmaxf(m, __shfl_xor(m, o));
    float z = 0.f;
    for (int j = ln; j < NN; j += 64) z += __expf(sc_s[row][j] - m);
    #pragma unroll
    for (int o = 32; o; o >>= 1) z += __shfl_xor(z, o);
    if (ln == 0) { mz_s[row][0] = m; mz_s[row][1] = 1.f/z; }
  }
  __syncthreads();

  // attn (mean over heads) + assign softmax over S, thread = node
  {
    float at[SS];
    #pragma unroll
    for (int s = 0; s < SS; ++s) {
      float a = 0.f;
      #pragma unroll
      for (int h = 0; h < HH; ++h) {
        int row = h*SS+s;
        a += __expf(sc_s[row][tid] - mz_s[row][0]) * mz_s[row][1];
      }
      at[s] = a * 0.25f;
    }
    float m = fmaxf(fmaxf(at[0],at[1]), fmaxf(at[2],at[3]));
    float e0=__expf(at[0]-m), e1=__expf(at[1]-m), e2=__expf(at[2]-m), e3=__expf(at[3]-m);
    float zi = 1.f/(e0+e1+e2+e3);
    float4 av = make_float4(e0*zi, e1*zi, e2*zi, e3*zi);
    as_s[tid][0]=av.x; as_s[tid][1]=av.y; as_s[tid][2]=av.z; as_s[tid][3]=av.w;
    reinterpret_cast<float4*>(assign_o)[(size_t)b*NN + tid] = av;
  }
  __syncthreads();

  // A_s = sum_n assign[n][s]  (wave wv handles s=wv)
  {
    float a = as_s[ln][wv] + as_s[ln+64][wv] + as_s[ln+128][wv] + as_s[ln+192][wv];
    #pragma unroll
    for (int o = 32; o; o >>= 1) a += __shfl_xor(a, o);
    if (ln == 0) As_s[wv] = a;
  }
  // t[s][c] = sum_n assign[n][s]*x[n][c]
  {
    int s = tid >> 6, c = tid & 63;
    float acc = 0.f;
    for (int n = 0; n < NN; ++n) acc += as_s[n][s] * x_s[n*(FF+1)+c];
    t_s[s][c] = acc;
  }
  __syncthreads();

  // sf[s][f] = sum_c t[s][c]*w_a2s[c][f] + A_s*b_a2s[f]
  for (int o = tid; o < SS*FSS; o += 256) {
    int s = o >> 7, f = o & 127;
    float acc = As_s[s] * b_a2s[f];
    for (int c = 0; c < FF; ++c) acc += t_s[s][c] * w_a2s[c*FSS+f];
    sf_o[((size_t)b*SS+s)*FSS+f] = acc;
  }
}

// ---------------------------------------------------------------- coarse graph conv (complete K4 graph)
__global__ __launch_bounds__(128) void k_coarse(
    const float* __restrict__ in, const float* __restrict__ W, const float* __restrict__ bias,
    const float* __restrict__ pmu, const float* __restrict__ prstd,
    const float* __restrict__ pgamma, const float* __restrict__ pbeta, int applyBN,
    float* __restrict__ out, float* __restrict__ stat1, float* __restrict__ stat2)
{
  const int b = blockIdx.x, f = threadIdx.x;
  __shared__ float x_s[SS][FSS];
  #pragma unroll
  for (int i = 0; i < SS; ++i) {
    float v = in[((size_t)b*SS+i)*FSS + f];
    if (applyBN) v = fmaxf((v - pmu[f])*prstd[f]*pgamma[f] + pbeta[f], 0.f);
    x_s[i][f] = v;
  }
  __syncthreads();
  float h0 = bias[f], h1 = h0, h2 = h0, h3 = h0;
  for (int c = 0; c < FSS; ++c) {
    float w = W[c*FSS+f];
    h0 += x_s[0][c]*w; h1 += x_s[1][c]*w; h2 += x_s[2][c]*w; h3 += x_s[3][c]*w;
  }
  float s4 = h0+h1+h2+h3;
  const float inv3 = 1.f/3.f;
  float o0 = h0 + (s4-h0)*inv3;
  float o1 = h1 + (s4-h1)*inv3;
  float o2 = h2 + (s4-h2)*inv3;
  float o3 = h3 + (s4-h3)*inv3;
  size_t ob = (size_t)b*SS*FSS + f;
  out[ob] = o0; out[ob+FSS] = o1; out[ob+2*FSS] = o2; out[ob+3*FSS] = o3;
  stat1[(size_t)f*BB + b] = o0+o1+o2+o3;
  stat2[(size_t)f*BB + b] = o0*o0+o1*o1+o2*o2+o3*o3;
}

// ---------------------------------------------------------------- BN stats reduce: one block per feature
__global__ __launch_bounds__(256) void k_bnstats(
    const float* __restrict__ s1, const float* __restrict__ s2,
    float* __restrict__ mu, float* __restrict__ rstd, float invcnt)
{
  const int f = blockIdx.x, tid = threadIdx.x;
  float a = 0.f, q = 0.f;
  for (int j = tid; j < BB; j += 256) { a += s1[(size_t)f*BB+j]; q += s2[(size_t)f*BB+j]; }
  #pragma unroll
  for (int o = 32; o; o >>= 1) { a += __shfl_xor(a, o); q += __shfl_xor(q, o); }
  __shared__ float ra[4], rq[4];
  int wv = tid >> 6;
  if ((tid & 63) == 0) { ra[wv] = a; rq[wv] = q; }
  __syncthreads();
  if (tid == 0) {
    float s = ra[0]+ra[1]+ra[2]+ra[3], ss = rq[0]+rq[1]+rq[2]+rq[3];
    float m = s*invcnt; float v = ss*invcnt - m*m;
    mu[f] = m; rstd[f] = 1.f / sqrtf(v + EPSF);
  }
}

// ---------------------------------------------------------------- kNN edges
__global__ __launch_bounds__(256) void k_knn(
    const float* __restrict__ pos, const float* __restrict__ pres,
    int* __restrict__ nbr_o, float* __restrict__ em_o, float* __restrict__ ivd_o)
{
  const int b = blockIdx.x, tid = threadIdx.x;
  const int ln = tid & 63, wv = tid >> 6;
  __shared__ float px[NN], py[NN], degs[NN];
  __shared__ int vld[NN];
  __shared__ int cnt_s[4];
  float2 p = reinterpret_cast<const float2*>(pos)[(size_t)b*NN + tid];
  float pr = pres[(size_t)b*NN + tid];
  int v = pr > 0.5f ? 1 : 0;
  px[tid] = p.x; py[tid] = p.y; vld[tid] = v; degs[tid] = 0.f;
  int cnt = v;
  #pragma unroll
  for (int o = 32; o; o >>= 1) cnt += __shfl_xor(cnt, o);
  if (ln == 0) cnt_s[wv] = cnt;
  __syncthreads();
  int nv = cnt_s[0]+cnt_s[1]+cnt_s[2]+cnt_s[3];

  // top-5 smallest (d2, j) lexicographic; strict-< insert == top_k tie-break (lower index first)
  float b0=3.4e38f, b1=b0, b2=b0, b3=b0, b4=b0;
  int   j0=0, j1=0, j2=0, j3=0, j4=0;
  float xi = p.x, yi = p.y;
  for (int j = 0; j < NN; ++j) {
    float dx = __fsub_rn(xi, px[j]);
    float dy = __fsub_rn(yi, py[j]);
    float d2 = __fadd_rn(__fmul_rn(dx,dx), __fmul_rn(dy,dy)); // no fma: match numpy
    if (!vld[j]) d2 = BIGF;
    if (d2 < b4) {
      b4 = d2; j4 = j;
      if (b4 < b3) { float t=b3; b3=b4; b4=t; int ti=j3; j3=j4; j4=ti; }
      if (b3 < b2) { float t=b2; b2=b3; b3=t; int ti=j2; j2=j3; j3=ti; }
      if (b2 < b1) { float t=b1; b1=b2; b2=t; int ti=j1; j1=j2; j2=ti; }
      if (b1 < b0) { float t=b0; b0=b1; b1=t; int ti=j0; j0=j1; j1=ti; }
    }
  }
  bool okrow = (v != 0) && (nv >= 2);
  size_t base = ((size_t)b*NN + tid)*KK;
  float dk[KK] = {b1,b2,b3,b4};
  int   jk[KK] = {j1,j2,j3,j4};
  #pragma unroll
  for (int k = 0; k < KK; ++k) {
    float em = (okrow && dk[k] < 0.5f*BIGF) ? 1.f : 0.f;
    nbr_o[base+k] = jk[k];
    em_o[base+k]  = em;
    if (em > 0.f) atomicAdd(&degs[jk[k]], 1.f);
  }
  __syncthreads();
  ivd_o[(size_t)b*NN + tid] = 1.f / fmaxf(degs[tid], 1.f);
}

// ---------------------------------------------------------------- ctx + af init
__global__ __launch_bounds__(256) void k_ctx(
    const float* __restrict__ axle, const float* __restrict__ hc1,
    const float* __restrict__ mu, const float* __restrict__ rstd,
    const float* __restrict__ gamma, const float* __restrict__ beta,
    const float* __restrict__ assign_i,
    const float* __restrict__ w_s2a, const float* __restrict__ b_s2a,
    float* __restrict__ af_o)
{
  const int b = blockIdx.x, tid = threadIdx.x;
  __shared__ float csf[SS][FSS];
  __shared__ float u_s[SS][FF];
  for (int i = tid; i < SS*FSS; i += 256) {
    int s = i >> 7, f = i & 127;
    float v = hc1[((size_t)b*SS+s)*FSS + f];
    csf[s][f] = fmaxf((v - mu[f])*rstd[f]*gamma[f] + beta[f], 0.f);
  }
  __syncthreads();
  {
    int s = tid >> 6, f = tid & 63;
    float acc = 0.f;
    for (int c = 0; c < FSS; ++c) acc += csf[s][c] * w_s2a[c*FF+f];
    u_s[s][f] = acc;
  }
  __syncthreads();
  const size_t gb = (size_t)b*NN*FF;
  for (int i = tid; i < NN*FF; i += 256) {
    int n = i >> 6, f = i & 63;
    const float* ag = assign_i + ((size_t)b*NN + n)*SS;
    float acc = axle[gb+i] + b_s2a[f]
              + ag[0]*u_s[0][f] + ag[1]*u_s[1][f] + ag[2]*u_s[2][f] + ag[3]*u_s[3][f];
    af_o[gb+i] = acc;
  }
}

// ---------------------------------------------------------------- fine graph conv (in-place on af)
__global__ __launch_bounds__(256) void k_fine(
    float* __restrict__ af,
    const float* __restrict__ W, const float* __restrict__ bias,
    const float* __restrict__ pmu, const float* __restrict__ prstd,
    const float* __restrict__ pgamma, const float* __restrict__ pbeta, int applyBN,
    const int* __restrict__ nbr, const float* __restrict__ em, const float* __restrict__ ivd,
    float* __restrict__ stat1, float* __restrict__ stat2)
{
  const int b = blockIdx.x, tid = threadIdx.x;
  const int wv = tid >> 6, ln = tid & 63;
  __shared__ float x_s[NN*(FF+1)];   // input, then reused as agg
  __shared__ float h_s[NN*(FF+1)];
  __shared__ float red1[4][FF], red2[4][FF];
  float* afb = af + (size_t)b*NN*FF;
  for (int i = tid; i < NN*FF; i += 256) {
    int n = i >> 6, f = i & 63;
    float v = afb[i];
    if (applyBN) v = fmaxf((v - pmu[f])*prstd[f]*pgamma[f] + pbeta[f], 0.f);
    x_s[n*(FF+1)+f] = v;
  }
  __syncthreads();
  // h = x @ W + b, thread = node
  {
    float acc[FF];
    #pragma unroll
    for (int f = 0; f < FF; ++f) acc[f] = bias[f];
    for (int c = 0; c < FF; ++c) {
      float xc = x_s[tid*(FF+1)+c];
      #pragma unroll
      for (int f = 0; f < FF; ++f) acc[f] += xc * W[c*FF+f];   // uniform -> s_load
    }
    #pragma unroll
    for (int f = 0; f < FF; ++f) h_s[tid*(FF+1)+f] = acc[f];
  }
  __syncthreads();
  for (int i = tid; i < NN*(FF+1); i += 256) x_s[i] = 0.f;     // x_s becomes agg
  __syncthreads();
  // scatter: wave per edge, lanes = features
  for (int e = wv; e < NN*KK; e += 4) {
    float eme = em[(size_t)b*NN*KK + e];
    if (eme > 0.f) {
      int src = e >> 2;
      int d = nbr[(size_t)b*NN*KK + e];
      atomicAdd(&x_s[d*(FF+1)+ln], h_s[src*(FF+1)+ln]);
    }
  }
  __syncthreads();
  // hsum + write-back + stats partials (each thread owns fixed feature f = tid&63)
  float ps = 0.f, pss = 0.f;
  for (int i = tid; i < NN*FF; i += 256) {
    int n = i >> 6, f = i & 63;
    float hs = h_s[n*(FF+1)+f] + x_s[n*(FF+1)+f] * ivd[(size_t)b*NN + n];
    afb[i] = hs;
    ps += hs; pss += hs*hs;
  }
  red1[wv][ln] = ps; red2[wv][ln] = pss;
  __syncthreads();
  if (tid < FF) {
    stat1[(size_t)tid*BB + b] = red1[0][tid]+red1[1][tid]+red1[2][tid]+red1[3][tid];
    stat2[(size_t)tid*BB + b] = red2[0][tid]+red2[1][tid]+red2[2][tid]+red2[3][tid];
  }
}

// ---------------------------------------------------------------- pooling + output head
__global__ __launch_bounds__(256) void k_pool(
    const float* __restrict__ af, const float* __restrict__ pres,
    const float* __restrict__ pmu, const float* __restrict__ prstd,
    const float* __restrict__ pgamma, const float* __restrict__ pbeta,
    const float* __restrict__ w_out, const float* __restrict__ b_out,
    float* __restrict__ out)
{
  const int b = blockIdx.x, tid = threadIdx.x;
  const int wv = tid >> 6, ln = tid & 63;
  __shared__ float g_s[FF];
  __shared__ float red1[4][FF];
  __shared__ float pr_s[4];
  float pw = pres[(size_t)b*NN + tid];
  float t = pw;
  #pragma unroll
  for (int o = 32; o; o >>= 1) t += __shfl_xor(t, o);
  if (ln == 0) pr_s[wv] = t;
  float ps = 0.f;
  const size_t gb = (size_t)b*NN*FF;
  for (int i = tid; i < NN*FF; i += 256) {
    int n = i >> 6, f = i & 63;
    float v = af[gb+i];
    v = fmaxf((v - pmu[f])*prstd[f]*pgamma[f] + pbeta[f], 0.f);
    ps += v * pres[(size_t)b*NN + n];
  }
  red1[wv][ln] = ps;
  __syncthreads();
  if (tid < FF) {
    float s = red1[0][tid]+red1[1][tid]+red1[2][tid]+red1[3][tid];
    float den = fmaxf(pr_s[0]+pr_s[1]+pr_s[2]+pr_s[3], 1e-8f);
    g_s[tid] = s / den;
  }
  __syncthreads();
  if (tid < OUTT) {
    float acc = b_out[tid];
    for (int f = 0; f < FF; ++f) acc += g_s[f] * w_out[f*OUTT + tid];
    out[(size_t)b*OUTT + tid] = acc;
  }
}

// ---------------------------------------------------------------- launch
extern "C" void kernel_launch(void* const* d_in, const int* in_sizes, int n_in,
                              void* d_out, int out_size, void* d_ws, size_t ws_size,
                              hipStream_t stream) {
  (void)in_sizes; (void)n_in; (void)out_size; (void)ws_size;
  const float* axle  = (const float*)d_in[0];
  const float* pos   = (const float*)d_in[1];
  const float* pres  = (const float*)d_in[2];
  const float* sq    = (const float*)d_in[3];
  const float* wq    = (const float*)d_in[4];
  const float* bq    = (const float*)d_in[5];
  const float* wk    = (const float*)d_in[6];
  const float* bk    = (const float*)d_in[7];
  const float* w_a2s = (const float*)d_in[8];
  const float* b_a2s = (const float*)d_in[9];
  const float* w_s2a = (const float*)d_in[10];
  const float* b_s2a = (const float*)d_in[11];
  const float* cW    = (const float*)d_in[12];
  const float* cb    = (const float*)d_in[13];
  const float* cg    = (const float*)d_in[14];
  const float* cbe   = (const float*)d_in[15];
  const float* fW    = (const float*)d_in[16];
  const float* fb    = (const float*)d_in[17];
  const float* fg    = (const float*)d_in[18];
  const float* fbe   = (const float*)d_in[19];
  const float* wout  = (const float*)d_in[20];
  const float* bout  = (const float*)d_in[21];
  float* out = (float*)d_out;

  char* base = (char*)d_ws;
  size_t off = 0;
  auto alloc = [&](size_t nbytes) -> void* {
    void* p = base + off; off += (nbytes + 255) & ~(size_t)255; return p;
  };
  float* af     = (float*)alloc((size_t)BB*NN*FF*4);
  float* assign = (float*)alloc((size_t)BB*NN*SS*4);
  float* sf     = (float*)alloc((size_t)BB*SS*FSS*4);
  float* hc0    = (float*)alloc((size_t)BB*SS*FSS*4);
  float* hc1    = (float*)alloc((size_t)BB*SS*FSS*4);
  int*   nbr    = (int*)  alloc((size_t)BB*NN*KK*4);
  float* em     = (float*)alloc((size_t)BB*NN*KK*4);
  float* ivd    = (float*)alloc((size_t)BB*NN*4);
  float* st1    = (float*)alloc((size_t)FSS*BB*4);
  float* st2    = (float*)alloc((size_t)FSS*BB*4);
  float* mu0    = (float*)alloc(FSS*4);
  float* rs0    = (float*)alloc(FSS*4);
  float* mu1    = (float*)alloc(FSS*4);
  float* rs1    = (float*)alloc(FSS*4);
  float* muF    = (float*)alloc(FF*4);
  float* rsF    = (float*)alloc(FF*4);

  k_attn_sf<<<BB, 256, 0, stream>>>(axle, sq, wq, bq, wk, bk, w_a2s, b_a2s, assign, sf);

  k_coarse<<<BB, 128, 0, stream>>>(sf,  cW,          cb,     mu0, rs0, cg, cbe, 0, hc0, st1, st2);
  k_bnstats<<<FSS, 256, 0, stream>>>(st1, st2, mu0, rs0, 1.f/((float)BB*SS));
  k_coarse<<<BB, 128, 0, stream>>>(hc0, cW+FSS*FSS,  cb+FSS, mu0, rs0, cg, cbe, 1, hc1, st1, st2);
  k_bnstats<<<FSS, 256, 0, stream>>>(st1, st2, mu1, rs1, 1.f/((float)BB*SS));

  k_knn<<<BB, 256, 0, stream>>>(pos, pres, nbr, em, ivd);

  k_ctx<<<BB, 256, 0, stream>>>(axle, hc1, mu1, rs1, cg+FSS, cbe+FSS, assign, w_s2a, b_s2a, af);

  k_fine<<<BB, 256, 0, stream>>>(af, fW,          fb,      muF, rsF, fg,      fbe,      0, nbr, em, ivd, st1, st2);
  k_bnstats<<<FF, 256, 0, stream>>>(st1, st2, muF, rsF, 1.f/((float)BB*NN));
  k_fine<<<BB, 256, 0, stream>>>(af, fW+FF*FF,    fb+FF,   muF, rsF, fg,      fbe,      1, nbr, em, ivd, st1, st2);
  k_bnstats<<<FF, 256, 0, stream>>>(st1, st2, muF, rsF, 1.f/((float)BB*NN));
  k_fine<<<BB, 256, 0, stream>>>(af, fW+2*FF*FF,  fb+2*FF, muF, rsF, fg+FF,   fbe+FF,   1, nbr, em, ivd, st1, st2);
  k_bnstats<<<FF, 256, 0, stream>>>(st1, st2, muF, rsF, 1.f/((float)BB*NN));

  k_pool<<<BB, 256, 0, stream>>>(af, pres, muF, rsF, fg+2*FF, fbe+2*FF, wout, bout, out);
}

// Round 2
// 477.452 us; speedup vs baseline: 2.9800x; 2.9800x over previous
//
#include <hip/hip_runtime.h>
#include <math.h>

#define BB   1024
#define NN   256
#define FF   64
#define FSS  128
#define OUTT 128
#define SS   4
#define HH   4
#define KK   4
#define HDD  16
#define EPSF 1e-5f
#define BIGF 1000000000.0f

// ---------------------------------------------------------------- K1: attention + assign + sf
__global__ __launch_bounds__(256) void k_attn_sf(
    const float* __restrict__ axle, const float* __restrict__ sq,
    const float* __restrict__ wq, const float* __restrict__ bq,
    const float* __restrict__ wk, const float* __restrict__ bk,
    const float* __restrict__ w_a2s, const float* __restrict__ b_a2s,
    float* __restrict__ assign_o, float* __restrict__ sf_o)
{
  const int b = blockIdx.x, tid = threadIdx.x;
  const int wv = tid >> 6, ln = tid & 63;
  __shared__ float x_s[NN*(FF+1)];
  __shared__ float sq_s[SS*FF];
  __shared__ float q_s[SS*FF];
  __shared__ float sc_s[HH*SS][NN];
  __shared__ float mz_s[HH*SS][2];
  __shared__ float as_s[NN][SS];
  __shared__ float t_s[SS][FF];
  __shared__ float As_s[SS];

  sq_s[tid] = sq[tid];
  const float* afb = axle + (size_t)b*NN*FF;
  for (int i = tid; i < NN*FF; i += 256)
    x_s[(i>>6)*(FF+1) + (i&63)] = afb[i];
  __syncthreads();

  {
    int s = tid >> 6, f = tid & 63;
    float acc = bq[f];
    for (int c = 0; c < FF; ++c) acc += sq_s[s*FF+c] * wq[c*FF+f];
    q_s[s*FF+f] = acc;
  }
  __syncthreads();

  {
    float acc[FF];
    #pragma unroll
    for (int f = 0; f < FF; ++f) acc[f] = bk[f];
    for (int c = 0; c < FF; ++c) {
      float xc = x_s[tid*(FF+1)+c];
      #pragma unroll
      for (int f = 0; f < FF; ++f) acc[f] += xc * wk[c*FF+f];
    }
    #pragma unroll
    for (int h = 0; h < HH; ++h) {
      #pragma unroll
      for (int s = 0; s < SS; ++s) {
        float sc = 0.f;
        #pragma unroll
        for (int d = 0; d < HDD; ++d) sc += q_s[s*FF + h*HDD + d] * acc[h*HDD + d];
        sc_s[h*SS+s][tid] = sc * 0.25f;
      }
    }
  }
  __syncthreads();

  for (int r = 0; r < 4; ++r) {
    int row = wv*4 + r;
    float m = -3.4e38f;
    for (int j = ln; j < NN; j += 64) m = fmaxf(m, sc_s[row][j]);
    #pragma unroll
    for (int o = 32; o; o >>= 1) m = fmaxf(m, __shfl_xor(m, o));
    float z = 0.f;
    for (int j = ln; j < NN; j += 64) z += __expf(sc_s[row][j] - m);
    #pragma unroll
    for (int o = 32; o; o >>= 1) z += __shfl_xor(z, o);
    if (ln == 0) { mz_s[row][0] = m; mz_s[row][1] = 1.f/z; }
  }
  __syncthreads();

  {
    float at[SS];
    #pragma unroll
    for (int s = 0; s < SS; ++s) {
      float a = 0.f;
      #pragma unroll
      for (int h = 0; h < HH; ++h) {
        int row = h*SS+s;
        a += __expf(sc_s[row][tid] - mz_s[row][0]) * mz_s[row][1];
      }
      at[s] = a * 0.25f;
    }
    float m = fmaxf(fmaxf(at[0],at[1]), fmaxf(at[2],at[3]));
    float e0=__expf(at[0]-m), e1=__expf(at[1]-m), e2=__expf(at[2]-m), e3=__expf(at[3]-m);
    float zi = 1.f/(e0+e1+e2+e3);
    float4 av = make_float4(e0*zi, e1*zi, e2*zi, e3*zi);
    as_s[tid][0]=av.x; as_s[tid][1]=av.y; as_s[tid][2]=av.z; as_s[tid][3]=av.w;
    reinterpret_cast<float4*>(assign_o)[(size_t)b*NN + tid] = av;
  }
  __syncthreads();

  {
    float a = as_s[ln][wv] + as_s[ln+64][wv] + as_s[ln+128][wv] + as_s[ln+192][wv];
    #pragma unroll
    for (int o = 32; o; o >>= 1) a += __shfl_xor(a, o);
    if (ln == 0) As_s[wv] = a;
  }
  {
    int s = tid >> 6, c = tid & 63;
    float acc = 0.f;
    for (int n = 0; n < NN; ++n) acc += as_s[n][s] * x_s[n*(FF+1)+c];
    t_s[s][c] = acc;
  }
  __syncthreads();

  for (int o = tid; o < SS*FSS; o += 256) {
    int s = o >> 7, f = o & 127;
    float acc = As_s[s] * b_a2s[f];
    for (int c = 0; c < FF; ++c) acc += t_s[s][c] * w_a2s[c*FSS+f];
    sf_o[((size_t)b*SS+s)*FSS+f] = acc;
  }
}

// ---------------------------------------------------------------- coarse graph conv (complete K4 graph)
__global__ __launch_bounds__(128) void k_coarse(
    const float* __restrict__ in, const float* __restrict__ W, const float* __restrict__ bias,
    const float* __restrict__ pmu, const float* __restrict__ prstd,
    const float* __restrict__ pgamma, const float* __restrict__ pbeta, int applyBN,
    float* __restrict__ out, float* __restrict__ stat1, float* __restrict__ stat2)
{
  const int b = blockIdx.x, f = threadIdx.x;
  __shared__ float x_s[SS][FSS];
  #pragma unroll
  for (int i = 0; i < SS; ++i) {
    float v = in[((size_t)b*SS+i)*FSS + f];
    if (applyBN) v = fmaxf((v - pmu[f])*prstd[f]*pgamma[f] + pbeta[f], 0.f);
    x_s[i][f] = v;
  }
  __syncthreads();
  float h0 = bias[f], h1 = h0, h2 = h0, h3 = h0;
  for (int c = 0; c < FSS; ++c) {
    float w = W[c*FSS+f];
    h0 += x_s[0][c]*w; h1 += x_s[1][c]*w; h2 += x_s[2][c]*w; h3 += x_s[3][c]*w;
  }
  float s4 = h0+h1+h2+h3;
  const float inv3 = 1.f/3.f;
  float o0 = h0 + (s4-h0)*inv3;
  float o1 = h1 + (s4-h1)*inv3;
  float o2 = h2 + (s4-h2)*inv3;
  float o3 = h3 + (s4-h3)*inv3;
  size_t ob = (size_t)b*SS*FSS + f;
  out[ob] = o0; out[ob+FSS] = o1; out[ob+2*FSS] = o2; out[ob+3*FSS] = o3;
  stat1[(size_t)f*BB + b] = o0+o1+o2+o3;
  stat2[(size_t)f*BB + b] = o0*o0+o1*o1+o2*o2+o3*o3;
}

// ---------------------------------------------------------------- BN stats reduce: one block per feature
__global__ __launch_bounds__(256) void k_bnstats(
    const float* __restrict__ s1, const float* __restrict__ s2,
    float* __restrict__ mu, float* __restrict__ rstd, float invcnt)
{
  const int f = blockIdx.x, tid = threadIdx.x;
  float a = 0.f, q = 0.f;
  for (int j = tid; j < BB; j += 256) { a += s1[(size_t)f*BB+j]; q += s2[(size_t)f*BB+j]; }
  #pragma unroll
  for (int o = 32; o; o >>= 1) { a += __shfl_xor(a, o); q += __shfl_xor(q, o); }
  __shared__ float ra[4], rq[4];
  int wv = tid >> 6;
  if ((tid & 63) == 0) { ra[wv] = a; rq[wv] = q; }
  __syncthreads();
  if (tid == 0) {
    float s = ra[0]+ra[1]+ra[2]+ra[3], ss = rq[0]+rq[1]+rq[2]+rq[3];
    float m = s*invcnt; float v = ss*invcnt - m*m;
    mu[f] = m; rstd[f] = 1.f / sqrtf(v + EPSF);
  }
}

// ---------------------------------------------------------------- kNN edges + reverse-CSR build
__global__ __launch_bounds__(256) void k_knn(
    const float* __restrict__ pos, const float* __restrict__ pres,
    int* __restrict__ rev_go, int* __restrict__ offs_go,
    float* __restrict__ ivd_o, float* __restrict__ bf_o)
{
  const int b = blockIdx.x, tid = threadIdx.x;
  const int ln = tid & 63, wv = tid >> 6;
  __shared__ float px[NN], py[NN];
  __shared__ int vld[NN];
  __shared__ int wcnt[4];
  __shared__ int nbr_s[NN*KK];
  __shared__ int cnti[NN], scn[NN], cur[NN];
  __shared__ __align__(16) int rev_s[NN*KK];
  float2 p = reinterpret_cast<const float2*>(pos)[(size_t)b*NN + tid];
  float pr = pres[(size_t)b*NN + tid];
  int v = pr > 0.5f ? 1 : 0;
  px[tid] = p.x; py[tid] = p.y; vld[tid] = v;
  cnti[tid] = 0; cur[tid] = 0;
  #pragma unroll
  for (int k = 0; k < KK; ++k) rev_s[tid*KK+k] = 0;
  int cnt = v;
  #pragma unroll
  for (int o = 32; o; o >>= 1) cnt += __shfl_xor(cnt, o);
  if (ln == 0) wcnt[wv] = cnt;
  __syncthreads();
  int nv = wcnt[0]+wcnt[1]+wcnt[2]+wcnt[3];

  // top-5 smallest (d2, j) lexicographic; strict-< insert == top_k tie-break
  float b0=3.4e38f, b1=b0, b2=b0, b3=b0, b4=b0;
  int   j0=0, j1=0, j2=0, j3=0, j4=0;
  float xi = p.x, yi = p.y;
  for (int j = 0; j < NN; ++j) {
    float dx = __fsub_rn(xi, px[j]);
    float dy = __fsub_rn(yi, py[j]);
    float d2 = __fadd_rn(__fmul_rn(dx,dx), __fmul_rn(dy,dy)); // no fma: match numpy
    if (!vld[j]) d2 = BIGF;
    if (d2 < b4) {
      b4 = d2; j4 = j;
      if (b4 < b3) { float t=b3; b3=b4; b4=t; int ti=j3; j3=j4; j4=ti; }
      if (b3 < b2) { float t=b2; b2=b3; b3=t; int ti=j2; j2=j3; j3=ti; }
      if (b2 < b1) { float t=b1; b1=b2; b2=t; int ti=j1; j1=j2; j2=ti; }
      if (b1 < b0) { float t=b0; b0=b1; b1=t; int ti=j0; j0=j1; j1=ti; }
    }
  }
  (void)j0;
  bool okrow = (v != 0) && (nv >= 2);
  int d0 = (okrow && b1 < 0.5f*BIGF) ? j1 : -1;
  int d1 = (okrow && b2 < 0.5f*BIGF) ? j2 : -1;
  int d2i= (okrow && b3 < 0.5f*BIGF) ? j3 : -1;
  int d3 = (okrow && b4 < 0.5f*BIGF) ? j4 : -1;
  nbr_s[tid*KK+0] = d0; nbr_s[tid*KK+1] = d1;
  nbr_s[tid*KK+2] = d2i; nbr_s[tid*KK+3] = d3;
  if (d0 >= 0) atomicAdd(&cnti[d0], 1);
  if (d1 >= 0) atomicAdd(&cnti[d1], 1);
  if (d2i>= 0) atomicAdd(&cnti[d2i],1);
  if (d3 >= 0) atomicAdd(&cnti[d3], 1);
  __syncthreads();

  // inclusive scan of cnti -> scn
  scn[tid] = cnti[tid];
  __syncthreads();
  for (int d = 1; d < NN; d <<= 1) {
    int t = (tid >= d) ? scn[tid-d] : 0;
    __syncthreads();
    scn[tid] += t;
    __syncthreads();
  }
  // fill reverse lists
  #pragma unroll
  for (int k = 0; k < KK; ++k) {
    int d = nbr_s[tid*KK+k];
    if (d >= 0) {
      int pp = atomicAdd(&cur[d], 1);
      rev_s[scn[d] - cnti[d] + pp] = tid;
    }
  }
  __syncthreads();

  int start = scn[tid] - cnti[tid];
  offs_go[(size_t)b*(NN+1) + tid] = start;
  if (tid == NN-1) offs_go[(size_t)b*(NN+1) + NN] = scn[NN-1];
  float cf = (float)cnti[tid];
  ivd_o[(size_t)b*NN + tid] = 1.f / fmaxf(cf, 1.f);
  bf_o[(size_t)b*NN + tid]  = cnti[tid] > 0 ? 2.f : 1.f;
  reinterpret_cast<int4*>(rev_go)[(size_t)b*NN + tid] =
      *reinterpret_cast<int4*>(&rev_s[tid*KK]);
}

// ---------------------------------------------------------------- ctx + af init
__global__ __launch_bounds__(256) void k_ctx(
    const float* __restrict__ axle, const float* __restrict__ hc1,
    const float* __restrict__ mu, const float* __restrict__ rstd,
    const float* __restrict__ gamma, const float* __restrict__ beta,
    const float* __restrict__ assign_i,
    const float* __restrict__ w_s2a, const float* __restrict__ b_s2a,
    float* __restrict__ af_o)
{
  const int b = blockIdx.x, tid = threadIdx.x;
  __shared__ float csf[SS][FSS];
  __shared__ float u_s[SS][FF];
  for (int i = tid; i < SS*FSS; i += 256) {
    int s = i >> 7, f = i & 127;
    float v = hc1[((size_t)b*SS+s)*FSS + f];
    csf[s][f] = fmaxf((v - mu[f])*rstd[f]*gamma[f] + beta[f], 0.f);
  }
  __syncthreads();
  {
    int s = tid >> 6, f = tid & 63;
    float acc = 0.f;
    for (int c = 0; c < FSS; ++c) acc += csf[s][c] * w_s2a[c*FF+f];
    u_s[s][f] = acc;
  }
  __syncthreads();
  const size_t gb = (size_t)b*NN*FF;
  for (int i = tid; i < NN*FF; i += 256) {
    int n = i >> 6, f = i & 63;
    const float* ag = assign_i + ((size_t)b*NN + n)*SS;
    float acc = axle[gb+i] + b_s2a[f]
              + ag[0]*u_s[0][f] + ag[1]*u_s[1][f] + ag[2]*u_s[2][f] + ag[3]*u_s[3][f];
    af_o[gb+i] = acc;
  }
}

// ---------------------------------------------------------------- fine graph conv v2
// out = y @ W + b*bf,  y[n] = xbn[n] + ivd[n] * sum_{in-edges} xbn[src]
// (linearity: aggregate in x-space, single GEMM). In-place on af.
__global__ __launch_bounds__(512, 4) void k_fine2(
    float* __restrict__ af,
    const float* __restrict__ W, const float* __restrict__ bias,
    const float* __restrict__ pmu, const float* __restrict__ prstd,
    const float* __restrict__ pgamma, const float* __restrict__ pbeta, int applyBN,
    const int* __restrict__ rev_g, const int* __restrict__ offs_g,
    const float* __restrict__ ivd_g, const float* __restrict__ bf_g,
    float* __restrict__ stat1, float* __restrict__ stat2)
{
  const int b = blockIdx.x, tid = threadIdx.x;
  const int wv = tid >> 6, ln = tid & 63;
  __shared__ __align__(16) float x_s[NN*FF];        // 64 KB, x -> y in place
  __shared__ int rev_s[NN*KK];
  __shared__ int offs_s[NN+1];
  __shared__ float ivd_s[NN], bf_s[NN];
  __shared__ float scale_s[FF], shift_s[FF];
  __shared__ float red1[8][FF], red2[8][FF];

  if (tid < FF) {
    if (applyBN) {
      float sc = prstd[tid]*pgamma[tid];
      scale_s[tid] = sc; shift_s[tid] = pbeta[tid] - pmu[tid]*sc;
    } else { scale_s[tid] = 1.f; shift_s[tid] = 0.f; }
  }
  for (int i = tid; i < NN*KK; i += 512) rev_s[i] = rev_g[(size_t)b*NN*KK + i];
  if (tid <= NN) offs_s[tid] = offs_g[(size_t)b*(NN+1) + tid];
  if (tid < NN) { ivd_s[tid] = ivd_g[(size_t)b*NN + tid]; bf_s[tid] = bf_g[(size_t)b*NN + tid]; }
  __syncthreads();

  float* afb = af + (size_t)b*NN*FF;
  const float4* in4 = reinterpret_cast<const float4*>(afb);
  for (int i4 = tid; i4 < NN*FF/4; i4 += 512) {
    float4 v = in4[i4];
    int c0 = (i4*4) & (FF-1);
    v.x = v.x*scale_s[c0+0] + shift_s[c0+0];
    v.y = v.y*scale_s[c0+1] + shift_s[c0+1];
    v.z = v.z*scale_s[c0+2] + shift_s[c0+2];
    v.w = v.w*scale_s[c0+3] + shift_s[c0+3];
    if (applyBN) { v.x=fmaxf(v.x,0.f); v.y=fmaxf(v.y,0.f); v.z=fmaxf(v.z,0.f); v.w=fmaxf(v.w,0.f); }
    *reinterpret_cast<float4*>(&x_s[i4*4]) = v;
  }
  __syncthreads();

  // gather phase: wave wv owns nodes [wv*32, wv*32+32), lane = feature.
  // y held in named registers (static indexing) until all waves finish reading x.
  const int nb = wv << 5;
#define GATH(J) float y##J; { const int n_ = nb + (J); \
    const int s0_ = offs_s[n_]; const int s1_ = offs_s[n_+1]; \
    float sum_ = 0.f; \
    for (int i_ = s0_; i_ < s1_; ++i_) sum_ += x_s[rev_s[i_]*FF + ln]; \
    y##J = x_s[n_*FF + ln] + ivd_s[n_]*sum_; }
  GATH(0)  GATH(1)  GATH(2)  GATH(3)  GATH(4)  GATH(5)  GATH(6)  GATH(7)
  GATH(8)  GATH(9)  GATH(10) GATH(11) GATH(12) GATH(13) GATH(14) GATH(15)
  GATH(16) GATH(17) GATH(18) GATH(19) GATH(20) GATH(21) GATH(22) GATH(23)
  GATH(24) GATH(25) GATH(26) GATH(27) GATH(28) GATH(29) GATH(30) GATH(31)
#undef GATH
  __syncthreads();
#define WRB(J) x_s[(nb + (J))*FF + ln] = y##J;
  WRB(0)  WRB(1)  WRB(2)  WRB(3)  WRB(4)  WRB(5)  WRB(6)  WRB(7)
  WRB(8)  WRB(9)  WRB(10) WRB(11) WRB(12) WRB(13) WRB(14) WRB(15)
  WRB(16) WRB(17) WRB(18) WRB(19) WRB(20) WRB(21) WRB(22) WRB(23)
  WRB(24) WRB(25) WRB(26) WRB(27) WRB(28) WRB(29) WRB(30) WRB(31)
#undef WRB
  __syncthreads();

  // GEMM phase: out[n][ln] = sum_c y[n][c] * W[c][ln] + bf[n]*bias[ln]
  float wreg[FF];
  #pragma unroll
  for (int c = 0; c < FF; ++c) wreg[c] = W[c*FF + ln];   // coalesced, L1-resident
  float biasl = bias[ln];
  float ps = 0.f, pss = 0.f;
  for (int j = 0; j < 32; ++j) {
    int n = nb + j;
    float a0=0.f, a1=0.f, a2=0.f, a3=0.f;
    #pragma unroll
    for (int c = 0; c < FF; c += 4) {
      float4 y4 = *reinterpret_cast<const float4*>(&x_s[n*FF + c]);  // uniform ds_read_b128
      a0 = fmaf(y4.x, wreg[c+0], a0);
      a1 = fmaf(y4.y, wreg[c+1], a1);
      a2 = fmaf(y4.z, wreg[c+2], a2);
      a3 = fmaf(y4.w, wreg[c+3], a3);
    }
    float o = (a0+a1)+(a2+a3) + bf_s[n]*biasl;
    afb[n*FF + ln] = o;
    ps += o; pss += o*o;
  }
  red1[wv][ln] = ps; red2[wv][ln] = pss;
  __syncthreads();
  if (tid < FF) {
    float s = 0.f, ss = 0.f;
    #pragma unroll
    for (int w = 0; w < 8; ++w) { s += red1[w][tid]; ss += red2[w][tid]; }
    stat1[(size_t)tid*BB + b] = s;
    stat2[(size_t)tid*BB + b] = ss;
  }
}

// ---------------------------------------------------------------- pooling + output head
__global__ __launch_bounds__(256) void k_pool(
    const float* __restrict__ af, const float* __restrict__ pres,
    const float* __restrict__ pmu, const float* __restrict__ prstd,
    const float* __restrict__ pgamma, const float* __restrict__ pbeta,
    const float* __restrict__ w_out, const float* __restrict__ b_out,
    float* __restrict__ out)
{
  const int b = blockIdx.x, tid = threadIdx.x;
  const int wv = tid >> 6, ln = tid & 63;
  __shared__ float g_s[FF];
  __shared__ float red1[4][FF];
  __shared__ float pr_s[4];
  float pw = pres[(size_t)b*NN + tid];
  float t = pw;
  #pragma unroll
  for (int o = 32; o; o >>= 1) t += __shfl_xor(t, o);
  if (ln == 0) pr_s[wv] = t;
  float ps = 0.f;
  const size_t gb = (size_t)b*NN*FF;
  for (int i = tid; i < NN*FF; i += 256) {
    int n = i >> 6, f = i & 63;
    float v = af[gb+i];
    v = fmaxf((v - pmu[f])*prstd[f]*pgamma[f] + pbeta[f], 0.f);
    ps += v * pres[(size_t)b*NN + n];
  }
  red1[wv][ln] = ps;
  __syncthreads();
  if (tid < FF) {
    float s = red1[0][tid]+red1[1][tid]+red1[2][tid]+red1[3][tid];
    float den = fmaxf(pr_s[0]+pr_s[1]+pr_s[2]+pr_s[3], 1e-8f);
    g_s[tid] = s / den;
  }
  __syncthreads();
  if (tid < OUTT) {
    float acc = b_out[tid];
    for (int f = 0; f < FF; ++f) acc += g_s[f] * w_out[f*OUTT + tid];
    out[(size_t)b*OUTT + tid] = acc;
  }
}

// ---------------------------------------------------------------- launch
extern "C" void kernel_launch(void* const* d_in, const int* in_sizes, int n_in,
                              void* d_out, int out_size, void* d_ws, size_t ws_size,
                              hipStream_t stream) {
  (void)in_sizes; (void)n_in; (void)out_size; (void)ws_size;
  const float* axle  = (const float*)d_in[0];
  const float* pos   = (const float*)d_in[1];
  const float* pres  = (const float*)d_in[2];
  const float* sq    = (const float*)d_in[3];
  const float* wq    = (const float*)d_in[4];
  const float* bq    = (const float*)d_in[5];
  const float* wk    = (const float*)d_in[6];
  const float* bk    = (const float*)d_in[7];
  const float* w_a2s = (const float*)d_in[8];
  const float* b_a2s = (const float*)d_in[9];
  const float* w_s2a = (const float*)d_in[10];
  const float* b_s2a = (const float*)d_in[11];
  const float* cW    = (const float*)d_in[12];
  const float* cb    = (const float*)d_in[13];
  const float* cg    = (const float*)d_in[14];
  const float* cbe   = (const float*)d_in[15];
  const float* fW    = (const float*)d_in[16];
  const float* fb    = (const float*)d_in[17];
  const float* fg    = (const float*)d_in[18];
  const float* fbe   = (const float*)d_in[19];
  const float* wout  = (const float*)d_in[20];
  const float* bout  = (const float*)d_in[21];
  float* out = (float*)d_out;

  char* base = (char*)d_ws;
  size_t off = 0;
  auto alloc = [&](size_t nbytes) -> void* {
    void* p = base + off; off += (nbytes + 255) & ~(size_t)255; return p;
  };
  float* af     = (float*)alloc((size_t)BB*NN*FF*4);
  float* assign = (float*)alloc((size_t)BB*NN*SS*4);
  float* sf     = (float*)alloc((size_t)BB*SS*FSS*4);
  float* hc0    = (float*)alloc((size_t)BB*SS*FSS*4);
  float* hc1    = (float*)alloc((size_t)BB*SS*FSS*4);
  int*   rev    = (int*)  alloc((size_t)BB*NN*KK*4);
  int*   offs   = (int*)  alloc((size_t)BB*(NN+1)*4);
  float* ivd    = (float*)alloc((size_t)BB*NN*4);
  float* bff    = (float*)alloc((size_t)BB*NN*4);
  float* st1    = (float*)alloc((size_t)FSS*BB*4);
  float* st2    = (float*)alloc((size_t)FSS*BB*4);
  float* mu0    = (float*)alloc(FSS*4);
  float* rs0    = (float*)alloc(FSS*4);
  float* mu1    = (float*)alloc(FSS*4);
  float* rs1    = (float*)alloc(FSS*4);
  float* muF    = (float*)alloc(FF*4);
  float* rsF    = (float*)alloc(FF*4);

  k_attn_sf<<<BB, 256, 0, stream>>>(axle, sq, wq, bq, wk, bk, w_a2s, b_a2s, assign, sf);

  k_coarse<<<BB, 128, 0, stream>>>(sf,  cW,          cb,     mu0, rs0, cg, cbe, 0, hc0, st1, st2);
  k_bnstats<<<FSS, 256, 0, stream>>>(st1, st2, mu0, rs0, 1.f/((float)BB*SS));
  k_coarse<<<BB, 128, 0, stream>>>(hc0, cW+FSS*FSS,  cb+FSS, mu0, rs0, cg, cbe, 1, hc1, st1, st2);
  k_bnstats<<<FSS, 256, 0, stream>>>(st1, st2, mu1, rs1, 1.f/((float)BB*SS));

  k_knn<<<BB, 256, 0, stream>>>(pos, pres, rev, offs, ivd, bff);

  k_ctx<<<BB, 256, 0, stream>>>(axle, hc1, mu1, rs1, cg+FSS, cbe+FSS, assign, w_s2a, b_s2a, af);

  k_fine2<<<BB, 512, 0, stream>>>(af, fW,         fb,      muF, rsF, fg,    fbe,    0, rev, offs, ivd, bff, st1, st2);
  k_bnstats<<<FF, 256, 0, stream>>>(st1, st2, muF, rsF, 1.f/((float)BB*NN));
  k_fine2<<<BB, 512, 0, stream>>>(af, fW+FF*FF,   fb+FF,   muF, rsF, fg,    fbe,    1, rev, offs, ivd, bff, st1, st2);
  k_bnstats<<<FF, 256, 0, stream>>>(st1, st2, muF, rsF, 1.f/((float)BB*NN));
  k_fine2<<<BB, 512, 0, stream>>>(af, fW+2*FF*FF, fb+2*FF, muF, rsF, fg+FF, fbe+FF, 1, rev, offs, ivd, bff, st1, st2);
  k_bnstats<<<FF, 256, 0, stream>>>(st1, st2, muF, rsF, 1.f/((float)BB*NN));

  k_pool<<<BB, 256, 0, stream>>>(af, pres, muF, rsF, fg+2*FF, fbe+2*FF, wout, bout, out);
}